// Round 4
// baseline (253.861 us; speedup 1.0000x reference)
//
#include <hip/hip_runtime.h>
#include <stdint.h>

// Problem constants
#define B_SZ 1024
#define Z_SZ 32768
#define D_SZ 128
#define NZ   32                 // z chunks (split-Z)
#define CZ   (Z_SZ / NZ)        // 1024 z per chunk
#define TZ   64                 // z per inner tile
#define ITERS (CZ / TZ)         // 16
#define TBLK 64                 // batch rows per block (4 waves x 16)
#define WROWS 16                // batch rows per wave
#define ZW   (Z_SZ / 32)        // 1024 mask words per row

// LDS strides (elements). Row byte-strides must be 16B multiples for ds_read_b128,
// and every stride must be >= the row's element count (128 for d-rows, 64 for z-rows).
#define SEMB_STRIDE  136        // 64 x 136 bf16 (row-major emb tile), 272B rows
#define SEMBT_STRIDE 72         // 128 x 72 bf16 (transposed emb tile), 144B rows
#define SP_STRIDE    72         // 16 x 72 bf16 per wave (P tile), 144B rows
#define ST_STRIDE    136        // prep transpose staging rows hold 128 elems -> stride >= 128!

// prep grid split
#define NB_MASK ((B_SZ * ZW) / 256)   // 4096 blocks pack the bitmask
#define NB_TAB  (Z_SZ / 64)           // 512 blocks build bf16 tables

// Workspace layout (float offsets)
#define WS_O   0                              // [NZ][B][D]
#define WS_M   (NZ * B_SZ * D_SZ)             // [NZ][B]
#define WS_L   (WS_M + NZ * B_SZ)
#define WS_C   (WS_L + NZ * B_SZ)
#define WS_TAB (WS_C + NZ * B_SZ)             // embR [Z][D] bf16, embT [D][Z] bf16, mask [B][ZW] u32

typedef short bf16x8 __attribute__((ext_vector_type(8)));
typedef float f32x4  __attribute__((ext_vector_type(4)));

#if __has_builtin(__builtin_amdgcn_exp2f)
#define EXP2F(x) __builtin_amdgcn_exp2f(x)
#else
#define EXP2F(x) exp2f(x)
#endif

__device__ __forceinline__ unsigned short f2bf(float f) {
    union { float f; uint32_t u; } v; v.f = f;
    uint32_t u = v.u;
    u = (u + 0x7FFFu + ((u >> 16) & 1u)) >> 16;   // RNE truncate to bf16
    return (unsigned short)u;
}

// ---------------------------------------------------------------------------
// Fused prep:
//   blocks [0, NB_MASK):       z_sparse -> bitmask  (BW-bound streaming)
//   blocks [NB_MASK, +NB_TAB): emb f32 -> bf16 embR [Z][D] and embT [D][Z]
// ---------------------------------------------------------------------------
__global__ __launch_bounds__(256) void prep(
    const int*      __restrict__ zs,
    const float*    __restrict__ emb,
    unsigned short* __restrict__ embR,
    unsigned short* __restrict__ embT,
    uint32_t*       __restrict__ maskp)
{
    __shared__ __align__(16) unsigned short st[64 * ST_STRIDE];
    if (blockIdx.x < NB_MASK) {
        // ---- bitmask pack: thread packs 32 consecutive z of one row into one u32 ----
        const int gid = blockIdx.x * 256 + threadIdx.x;       // == b*ZW + w ; b*Z_SZ == gid*32
        const int4* src = (const int4*)(zs + (size_t)gid * 32);
        uint32_t mbits = 0;
#pragma unroll
        for (int k = 0; k < 8; ++k) {
            int4 v = src[k];
            mbits |= (v.x > 0 ? 1u : 0u) << (4 * k + 0);
            mbits |= (v.y > 0 ? 1u : 0u) << (4 * k + 1);
            mbits |= (v.z > 0 ? 1u : 0u) << (4 * k + 2);
            mbits |= (v.w > 0 ? 1u : 0u) << (4 * k + 3);
        }
        maskp[gid] = mbits;
        return;
    }

    // ---- bf16 tables for one 64-z tile (identical staging to the R1-verified kernel) ----
    const int z0 = (blockIdx.x - NB_MASK) * 64;
    const int t  = threadIdx.x;
    {
        const int r = t >> 2, q = t & 3;
        const float* src = emb + (size_t)(z0 + r) * D_SZ + q * 32;
        unsigned short* dR = embR + (size_t)(z0 + r) * D_SZ + q * 32;
        unsigned short* dL = st + r * ST_STRIDE + q * 32;
#pragma unroll
        for (int u = 0; u < 8; ++u) {
            float4 x = *(const float4*)(src + 4 * u);
            ushort4 h;
            h.x = f2bf(x.x); h.y = f2bf(x.y); h.z = f2bf(x.z); h.w = f2bf(x.w);
            *(ushort4*)(dR + 4 * u) = h;
            *(ushort4*)(dL + 4 * u) = h;   // 8B-aligned: rows are 272B (16B multiple)
        }
    }
    __syncthreads();
    {
        const int lane = t & 63, w = t >> 6;
#pragma unroll
        for (int i = 0; i < 4; ++i) {
            const int d = w * 32 + i * 8 + (lane >> 3);   // 0..127
            const int c = lane & 7;                       // 8-z chunk
            bf16x8 v;
#pragma unroll
            for (int k = 0; k < 8; ++k) v[k] = (short)st[(c * 8 + k) * ST_STRIDE + d];
            *(bf16x8*)(embT + (size_t)d * Z_SZ + z0 + c * 8) = v;
        }
    }
}

// ---------------------------------------------------------------------------
// attn_part, S^T form:
//   GEMM1: sfr[nt] = mfma(emb_rows, ctx)   -> lane holds S[b=l15][z'=16nt+4quad+r]
//   softmax: in-lane tree + 2 shfl_xor; T13 defer-max (THR=8)
//   GEMM2 (O^T): acc2[nt2] = mfma(embT_rows, P^T) -> lane holds O[d=16nt2+4quad+r][b=l15]
// ---------------------------------------------------------------------------
__global__ __launch_bounds__(256, 2) void attn_part(
    const uint32_t*       __restrict__ maskp,
    const float*          __restrict__ ctx,
    const unsigned short* __restrict__ embR,
    const unsigned short* __restrict__ embT,
    float*                __restrict__ ws)
{
    __shared__ __align__(16) unsigned short s_emb [TZ   * SEMB_STRIDE];   // 17408 B
    __shared__ __align__(16) unsigned short s_embT[D_SZ * SEMBT_STRIDE];  // 18432 B
    __shared__ __align__(16) unsigned short s_P   [4 * WROWS * SP_STRIDE];// 9216 B

    const int tid  = threadIdx.x;
    const int wave = tid >> 6;
    const int lane = tid & 63;
    const int l15  = lane & 15;
    const int quad = lane >> 4;

    const int bg     = blockIdx.x;            // 0..15 batch group
    const int ch     = blockIdx.y;            // 0..31 z-chunk
    const int z_base = ch * CZ;
    const int wb0    = bg * TBLK + wave * WROWS;  // first batch row of this wave
    const int brow   = wb0 + l15;                 // this lane's batch row

    // staging thread mappings (fixed for the whole kernel)
    const int srow = tid >> 2, sq3 = tid & 3;   // row tile: 64B per thread
    const int sd   = tid >> 1, sh  = tid & 1;   // transposed tile: 64B per thread

    // ---- ctx B-fragments, scaled by log2(e)/sqrt(D) (base-2 softmax), in regs ----
    // B-frag for mfma_16x16x32: lane holds B[k = quad*8+j][col = l15] = ctx[brow][k]
    bf16x8 afrag[4];
    {
        const float scale = (float)(1.4426950408889634 * 0.08838834764831845);
        const float* crow = ctx + (size_t)brow * D_SZ;
#pragma unroll
        for (int ks = 0; ks < 4; ++ks) {
            const float* p = crow + ks * 32 + quad * 8;
            float4 x0 = *(const float4*)(p);
            float4 x1 = *(const float4*)(p + 4);
            bf16x8 a;
            a[0] = (short)f2bf(x0.x * scale); a[1] = (short)f2bf(x0.y * scale);
            a[2] = (short)f2bf(x0.z * scale); a[3] = (short)f2bf(x0.w * scale);
            a[4] = (short)f2bf(x1.x * scale); a[5] = (short)f2bf(x1.y * scale);
            a[6] = (short)f2bf(x1.z * scale); a[7] = (short)f2bf(x1.w * scale);
            afrag[ks] = a;
        }
    }

    // ---- per-lane online-softmax state for row b = brow (replicated across quads) ----
    float m_s = -1e30f, l_s = 0.f;
    int   cnt = 0;
    f32x4 acc2[8];
#pragma unroll
    for (int n = 0; n < 8; ++n) { acc2[n][0]=0.f; acc2[n][1]=0.f; acc2[n][2]=0.f; acc2[n][3]=0.f; }

    // ---- T14 async-STAGE registers: next tile's emb fragments + mask words ----
    bf16x8 rA[4], rT[4];
    uint2  mv, mvn;
    {
        const unsigned short* srcR = embR + (size_t)(z_base + srow) * D_SZ + sq3 * 32;
        const unsigned short* srcT = embT + (size_t)sd * Z_SZ + z_base + sh * 32;
#pragma unroll
        for (int u = 0; u < 4; ++u) {
            rA[u] = *(const bf16x8*)(srcR + u * 8);
            rT[u] = *(const bf16x8*)(srcT + u * 8);
        }
        mv = *(const uint2*)(maskp + (size_t)brow * ZW + (z_base >> 5));
    }

    for (int it = 0; it < ITERS; ++it) {
        __syncthreads();   // previous tile's LDS reads complete

        // ---- write staged registers to LDS ----
        {
            unsigned short* dst = s_emb + srow * SEMB_STRIDE + sq3 * 32;
#pragma unroll
            for (int u = 0; u < 4; ++u) *(bf16x8*)(dst + u * 8) = rA[u];
        }
        {
            unsigned short* dst = s_embT + sd * SEMBT_STRIDE + sh * 32;
#pragma unroll
            for (int u = 0; u < 4; ++u) *(bf16x8*)(dst + u * 8) = rT[u];
        }

        __syncthreads();   // staging visible

        // ---- issue next tile's global loads; latency hides under MFMA/softmax ----
        if (it + 1 < ITERS) {
            const int z0n = z_base + (it + 1) * TZ;
            const unsigned short* srcR = embR + (size_t)(z0n + srow) * D_SZ + sq3 * 32;
            const unsigned short* srcT = embT + (size_t)sd * Z_SZ + z0n + sh * 32;
#pragma unroll
            for (int u = 0; u < 4; ++u) {
                rA[u] = *(const bf16x8*)(srcR + u * 8);
                rT[u] = *(const bf16x8*)(srcT + u * 8);
            }
            mvn = *(const uint2*)(maskp + (size_t)brow * ZW + (z0n >> 5));
        }

        // ---- GEMM1: S^T tiles; lane gets S[b=l15][z' = nt*16 + quad*4 + r] ----
        f32x4 sfr[4];
#pragma unroll
        for (int nt = 0; nt < 4; ++nt) {
            f32x4 c; c[0]=0.f; c[1]=0.f; c[2]=0.f; c[3]=0.f;
            const unsigned short* bb = s_emb + (nt * 16 + l15) * SEMB_STRIDE + quad * 8;
#pragma unroll
            for (int ks = 0; ks < 4; ++ks) {
                bf16x8 ef = *(const bf16x8*)(bb + ks * 32);
                c = __builtin_amdgcn_mfma_f32_16x16x32_bf16(ef, afrag[ks], c, 0, 0, 0);
            }
            sfr[nt] = c;
        }

        // ---- mask bits: z' = 16*nt + 4*quad + r ----
        const uint32_t w0 = mv.x >> (quad * 4);
        const uint32_t w1 = mv.y >> (quad * 4);
        int bit[4][4];
#pragma unroll
        for (int r = 0; r < 4; ++r) {
            bit[0][r] = (int)((w0 >> (r))      & 1u);
            bit[1][r] = (int)((w0 >> (16 + r)) & 1u);
            bit[2][r] = (int)((w1 >> (r))      & 1u);
            bit[3][r] = (int)((w1 >> (16 + r)) & 1u);
        }
        cnt += __popc(mv.x) + __popc(mv.y);   // per-row count (replicated across quads)

        // ---- masked max: in-lane tree + 2 cross-quad shuffles ----
        float tm = -1e30f;
#pragma unroll
        for (int nt = 0; nt < 4; ++nt) {
            float a0 = bit[nt][0] ? sfr[nt][0] : -1e30f;
            float a1 = bit[nt][1] ? sfr[nt][1] : -1e30f;
            float a2 = bit[nt][2] ? sfr[nt][2] : -1e30f;
            float a3 = bit[nt][3] ? sfr[nt][3] : -1e30f;
            tm = fmaxf(tm, fmaxf(fmaxf(a0, a1), fmaxf(a2, a3)));
        }
        tm = fmaxf(tm, __shfl_xor(tm, 16));
        tm = fmaxf(tm, __shfl_xor(tm, 32));

        // ---- T13 defer-max: only rescale when the max moved by > 8 (base-2) ----
        if (__any(tm > m_s + 8.f)) {
            float mnew = fmaxf(m_s, tm);
            float al = EXP2F(m_s - mnew);     // first active tile: exp2(-huge) = 0
            m_s = mnew;
            l_s *= al;
#pragma unroll
            for (int n = 0; n < 8; ++n) acc2[n] *= al;
        }

        // ---- P = mask ? 2^(S - m) : 0 ; pack to per-wave LDS (B-frag route) ----
        unsigned short* pwv = s_P + wave * (WROWS * SP_STRIDE) + l15 * SP_STRIDE + quad * 4;
        float ps = 0.f;
#pragma unroll
        for (int nt = 0; nt < 4; ++nt) {
            float p0 = bit[nt][0] ? EXP2F(sfr[nt][0] - m_s) : 0.f;
            float p1 = bit[nt][1] ? EXP2F(sfr[nt][1] - m_s) : 0.f;
            float p2 = bit[nt][2] ? EXP2F(sfr[nt][2] - m_s) : 0.f;
            float p3 = bit[nt][3] ? EXP2F(sfr[nt][3] - m_s) : 0.f;
            ps += (p0 + p1) + (p2 + p3);
            ushort4 h;
            h.x = f2bf(p0); h.y = f2bf(p1); h.z = f2bf(p2); h.w = f2bf(p3);
            *(ushort4*)(pwv + nt * 16) = h;   // s_P[b=l15][z' = 16nt + 4quad + 0..3]
        }
        ps += __shfl_xor(ps, 16);
        ps += __shfl_xor(ps, 32);
        l_s += ps;

        // ---- GEMM2 (O^T): acc2[nt2] += embT_rows @ P^T  (K = 64 via two slices) ----
        const unsigned short* pb = s_P + wave * (WROWS * SP_STRIDE) + l15 * SP_STRIDE + quad * 8;
        bf16x8 pA0 = *(const bf16x8*)(pb);        // P[b=l15][z = quad*8 + j], z<32
        bf16x8 pA1 = *(const bf16x8*)(pb + 32);   // z >= 32
#pragma unroll
        for (int nt2 = 0; nt2 < 8; ++nt2) {
            const unsigned short* tb = s_embT + (nt2 * 16 + l15) * SEMBT_STRIDE + quad * 8;
            bf16x8 e0 = *(const bf16x8*)(tb);
            bf16x8 e1 = *(const bf16x8*)(tb + 32);
            acc2[nt2] = __builtin_amdgcn_mfma_f32_16x16x32_bf16(e0, pA0, acc2[nt2], 0, 0, 0);
            acc2[nt2] = __builtin_amdgcn_mfma_f32_16x16x32_bf16(e1, pA1, acc2[nt2], 0, 0, 0);
        }

        mv = mvn;
    }

    // ---- epilogue: O rows are lane-local -> 8 vector stores; stats from quad 0 ----
    {
        float* orow = ws + WS_O + ((size_t)ch * B_SZ + brow) * D_SZ;
#pragma unroll
        for (int nt2 = 0; nt2 < 8; ++nt2) {
            *(f32x4*)(orow + nt2 * 16 + quad * 4) = acc2[nt2];
        }
    }
    if (lane < 16) {
        ws[WS_M + ch * B_SZ + brow] = m_s;
        ws[WS_L + ch * B_SZ + brow] = l_s;
        ws[WS_C + ch * B_SZ + brow] = (float)cnt;
    }
}

__global__ __launch_bounds__(128) void attn_reduce(
    const float* __restrict__ ws, float* __restrict__ out)
{
    const int b = blockIdx.x;
    const int d = threadIdx.x;
    const float* mP = ws + WS_M;
    const float* lP = ws + WS_L;
    const float* cP = ws + WS_C;

    float M = -1e30f;
#pragma unroll
    for (int c = 0; c < NZ; ++c) M = fmaxf(M, mP[c * B_SZ + b]);

    float L = 0.f, C = 0.f, acc = 0.f;
#pragma unroll
    for (int c = 0; c < NZ; ++c) {
        float w = EXP2F(mP[c * B_SZ + b] - M);
        L += lP[c * B_SZ + b] * w;
        C += cP[c * B_SZ + b];
        acc += ws[WS_O + ((size_t)c * B_SZ + b) * D_SZ + d] * w;
    }
    float cntv = fmaxf(C, 1.0f);
    out[(size_t)b * D_SZ + d] = (L > 0.f) ? acc / (L * cntv) : 0.f;
}

extern "C" void kernel_launch(void* const* d_in, const int* in_sizes, int n_in,
                              void* d_out, int out_size, void* d_ws, size_t ws_size,
                              hipStream_t stream) {
    (void)in_sizes; (void)n_in; (void)out_size; (void)ws_size;
    const int*   zs  = (const int*)  d_in[0];
    const float* ctx = (const float*)d_in[1];
    const float* emb = (const float*)d_in[2];
    float* out = (float*)d_out;
    float* ws  = (float*)d_ws;

    unsigned short* embR  = (unsigned short*)(ws + WS_TAB);
    unsigned short* embT  = embR + (size_t)Z_SZ * D_SZ;
    uint32_t*       maskp = (uint32_t*)(embT + (size_t)Z_SZ * D_SZ);

    prep<<<NB_MASK + NB_TAB, 256, 0, stream>>>(zs, emb, embR, embT, maskp);

    dim3 grid1(B_SZ / TBLK, NZ);   // (16, 32)
    attn_part<<<grid1, 256, 0, stream>>>(maskp, ctx, embR, embT, ws);
    attn_reduce<<<B_SZ, 128, 0, stream>>>(ws, out);
}

// Round 5
// 240.620 us; speedup vs baseline: 1.0550x; 1.0550x over previous
//
#include <hip/hip_runtime.h>
#include <stdint.h>

// Problem constants
#define B_SZ 1024
#define Z_SZ 32768
#define D_SZ 128
#define NZ   32                 // z chunks (split-Z)
#define CZ   (Z_SZ / NZ)        // 1024 z per chunk
#define TZ   64                 // z per inner tile
#define ITERS (CZ / TZ)         // 16
#define TBLK 64                 // batch rows per block (4 waves x 16)
#define WROWS 16                // batch rows per wave

// LDS strides (elements). Row byte-strides must be 16B multiples for ds_read_b128,
// and every stride must be >= the row's element count (128 for d-rows, 64 for z-rows).
#define SEMB_STRIDE  136        // 64 x 136 bf16 (row-major emb tile), 272B rows
#define SEMBT_STRIDE 72         // 128 x 72 bf16 (transposed emb tile), 144B rows
#define SP_STRIDE    72         // 16 x 72 bf16 per wave (P tile), 144B rows
#define ST_STRIDE    136        // prep transpose staging rows hold 128 elems -> stride >= 128

#define NB_TAB  (Z_SZ / 64)     // 512 blocks build bf16 tables

// Workspace layout (float offsets)
#define WS_O   0                              // [NZ][B][D]
#define WS_M   (NZ * B_SZ * D_SZ)             // [NZ][B]
#define WS_L   (WS_M + NZ * B_SZ)
#define WS_C   (WS_L + NZ * B_SZ)
#define WS_TAB (WS_C + NZ * B_SZ)             // embR [Z][D] bf16, embT [D][Z] bf16

typedef short bf16x8 __attribute__((ext_vector_type(8)));
typedef float f32x4  __attribute__((ext_vector_type(4)));

#if __has_builtin(__builtin_amdgcn_exp2f)
#define EXP2F(x) __builtin_amdgcn_exp2f(x)
#else
#define EXP2F(x) exp2f(x)
#endif

__device__ __forceinline__ unsigned short f2bf(float f) {
    union { float f; uint32_t u; } v; v.f = f;
    uint32_t u = v.u;
    u = (u + 0x7FFFu + ((u >> 16) & 1u)) >> 16;   // RNE truncate to bf16
    return (unsigned short)u;
}

// ---------------------------------------------------------------------------
// Prep: emb f32 [Z][D] -> bf16 embR [Z][D] and embT [D][Z]  (one block / 64 z)
// ---------------------------------------------------------------------------
__global__ __launch_bounds__(256) void prep(
    const float*    __restrict__ emb,
    unsigned short* __restrict__ embR,
    unsigned short* __restrict__ embT)
{
    __shared__ __align__(16) unsigned short st[64 * ST_STRIDE];
    const int z0 = blockIdx.x * 64;
    const int t  = threadIdx.x;
    {
        const int r = t >> 2, q = t & 3;
        const float* src = emb + (size_t)(z0 + r) * D_SZ + q * 32;
        unsigned short* dR = embR + (size_t)(z0 + r) * D_SZ + q * 32;
        unsigned short* dL = st + r * ST_STRIDE + q * 32;
#pragma unroll
        for (int u = 0; u < 8; ++u) {
            float4 x = *(const float4*)(src + 4 * u);
            ushort4 h;
            h.x = f2bf(x.x); h.y = f2bf(x.y); h.z = f2bf(x.z); h.w = f2bf(x.w);
            *(ushort4*)(dR + 4 * u) = h;
            *(ushort4*)(dL + 4 * u) = h;
        }
    }
    __syncthreads();
    {
        const int lane = t & 63, w = t >> 6;
#pragma unroll
        for (int i = 0; i < 4; ++i) {
            const int d = w * 32 + i * 8 + (lane >> 3);   // 0..127
            const int c = lane & 7;                       // 8-z chunk
            bf16x8 v;
#pragma unroll
            for (int k = 0; k < 8; ++k) v[k] = (short)st[(c * 8 + k) * ST_STRIDE + d];
            *(bf16x8*)(embT + (size_t)d * Z_SZ + z0 + c * 8) = v;
        }
    }
}

// ---------------------------------------------------------------------------
// attn_part, S^T form:
//   GEMM1: sfr[nt] = mfma(emb_rows, ctx)   -> lane holds S[b=l15][z'=16nt+4quad+r]
//   mask:  int4 at zs[brow][z0 + nt*16 + quad*4] gives exactly bits for r=0..3
//          (z_sparse read ONCE across the grid; 4 quads of a row cover full 64B lines)
//   softmax: in-lane tree + 2 shfl_xor; T13 defer-max (THR=8)
//   GEMM2 (O^T): acc2[nt2] = mfma(embT_rows, P^T) -> lane holds O[d=16nt2+4quad+r][b=l15]
// ---------------------------------------------------------------------------
__global__ __launch_bounds__(256, 2) void attn_part(
    const int*            __restrict__ zs,
    const float*          __restrict__ ctx,
    const unsigned short* __restrict__ embR,
    const unsigned short* __restrict__ embT,
    float*                __restrict__ ws)
{
    __shared__ __align__(16) unsigned short s_emb [TZ   * SEMB_STRIDE];   // 17408 B
    __shared__ __align__(16) unsigned short s_embT[D_SZ * SEMBT_STRIDE];  // 18432 B
    __shared__ __align__(16) unsigned short s_P   [4 * WROWS * SP_STRIDE];// 9216 B

    const int tid  = threadIdx.x;
    const int wave = tid >> 6;
    const int lane = tid & 63;
    const int l15  = lane & 15;
    const int quad = lane >> 4;

    const int bg     = blockIdx.x;            // 0..15 batch group
    const int ch     = blockIdx.y;            // 0..31 z-chunk
    const int z_base = ch * CZ;
    const int wb0    = bg * TBLK + wave * WROWS;  // first batch row of this wave
    const int brow   = wb0 + l15;                 // this lane's batch row

    // staging thread mappings (fixed for the whole kernel)
    const int srow = tid >> 2, sq3 = tid & 3;   // row tile: 64B per thread
    const int sd   = tid >> 1, sh  = tid & 1;   // transposed tile: 64B per thread

    const int* zrow = zs + (size_t)brow * Z_SZ + quad * 4;   // lane's mask base

    // ---- ctx B-fragments, scaled by log2(e)/sqrt(D) (base-2 softmax), in regs ----
    bf16x8 afrag[4];
    {
        const float scale = (float)(1.4426950408889634 * 0.08838834764831845);
        const float* crow = ctx + (size_t)brow * D_SZ;
#pragma unroll
        for (int ks = 0; ks < 4; ++ks) {
            const float* p = crow + ks * 32 + quad * 8;
            float4 x0 = *(const float4*)(p);
            float4 x1 = *(const float4*)(p + 4);
            bf16x8 a;
            a[0] = (short)f2bf(x0.x * scale); a[1] = (short)f2bf(x0.y * scale);
            a[2] = (short)f2bf(x0.z * scale); a[3] = (short)f2bf(x0.w * scale);
            a[4] = (short)f2bf(x1.x * scale); a[5] = (short)f2bf(x1.y * scale);
            a[6] = (short)f2bf(x1.z * scale); a[7] = (short)f2bf(x1.w * scale);
            afrag[ks] = a;
        }
    }

    // ---- per-lane online-softmax state for row b = brow (replicated across quads) ----
    float m_s = -1e30f, l_s = 0.f;
    int   cnt = 0;      // per-lane partial count (this lane's 16 z'/tile); reduced at epilogue
    f32x4 acc2[8];
#pragma unroll
    for (int n = 0; n < 8; ++n) { acc2[n][0]=0.f; acc2[n][1]=0.f; acc2[n][2]=0.f; acc2[n][3]=0.f; }

    // ---- T14 async-STAGE registers: next tile's emb fragments + mask int4s ----
    bf16x8 rA[4], rT[4];
    int4   mc[4], mn[4];
    {
        const unsigned short* srcR = embR + (size_t)(z_base + srow) * D_SZ + sq3 * 32;
        const unsigned short* srcT = embT + (size_t)sd * Z_SZ + z_base + sh * 32;
#pragma unroll
        for (int u = 0; u < 4; ++u) {
            rA[u] = *(const bf16x8*)(srcR + u * 8);
            rT[u] = *(const bf16x8*)(srcT + u * 8);
        }
#pragma unroll
        for (int nt = 0; nt < 4; ++nt) mc[nt] = *(const int4*)(zrow + z_base + nt * 16);
    }

    for (int it = 0; it < ITERS; ++it) {
        __syncthreads();   // previous tile's LDS reads complete

        // ---- write staged registers to LDS ----
        {
            unsigned short* dst = s_emb + srow * SEMB_STRIDE + sq3 * 32;
#pragma unroll
            for (int u = 0; u < 4; ++u) *(bf16x8*)(dst + u * 8) = rA[u];
        }
        {
            unsigned short* dst = s_embT + sd * SEMBT_STRIDE + sh * 32;
#pragma unroll
            for (int u = 0; u < 4; ++u) *(bf16x8*)(dst + u * 8) = rT[u];
        }

        __syncthreads();   // staging visible

        // ---- issue next tile's global loads; latency hides under MFMA/softmax ----
        if (it + 1 < ITERS) {
            const int z0n = z_base + (it + 1) * TZ;
            const unsigned short* srcR = embR + (size_t)(z0n + srow) * D_SZ + sq3 * 32;
            const unsigned short* srcT = embT + (size_t)sd * Z_SZ + z0n + sh * 32;
#pragma unroll
            for (int u = 0; u < 4; ++u) {
                rA[u] = *(const bf16x8*)(srcR + u * 8);
                rT[u] = *(const bf16x8*)(srcT + u * 8);
            }
#pragma unroll
            for (int nt = 0; nt < 4; ++nt) mn[nt] = *(const int4*)(zrow + z0n + nt * 16);
        }

        // ---- GEMM1: S^T tiles; lane gets S[b=l15][z' = nt*16 + quad*4 + r] ----
        f32x4 sfr[4];
#pragma unroll
        for (int nt = 0; nt < 4; ++nt) {
            f32x4 c; c[0]=0.f; c[1]=0.f; c[2]=0.f; c[3]=0.f;
            const unsigned short* bb = s_emb + (nt * 16 + l15) * SEMB_STRIDE + quad * 8;
#pragma unroll
            for (int ks = 0; ks < 4; ++ks) {
                bf16x8 ef = *(const bf16x8*)(bb + ks * 32);
                c = __builtin_amdgcn_mfma_f32_16x16x32_bf16(ef, afrag[ks], c, 0, 0, 0);
            }
            sfr[nt] = c;
        }

        // ---- mask bits straight from int4 components: z' = 16nt + 4quad + r ----
        int bit[4][4];
#pragma unroll
        for (int nt = 0; nt < 4; ++nt) {
            bit[nt][0] = (mc[nt].x > 0) ? 1 : 0;
            bit[nt][1] = (mc[nt].y > 0) ? 1 : 0;
            bit[nt][2] = (mc[nt].z > 0) ? 1 : 0;
            bit[nt][3] = (mc[nt].w > 0) ? 1 : 0;
            cnt += bit[nt][0] + bit[nt][1] + bit[nt][2] + bit[nt][3];
        }

        // ---- masked max: in-lane tree + 2 cross-quad shuffles ----
        float tm = -1e30f;
#pragma unroll
        for (int nt = 0; nt < 4; ++nt) {
            float a0 = bit[nt][0] ? sfr[nt][0] : -1e30f;
            float a1 = bit[nt][1] ? sfr[nt][1] : -1e30f;
            float a2 = bit[nt][2] ? sfr[nt][2] : -1e30f;
            float a3 = bit[nt][3] ? sfr[nt][3] : -1e30f;
            tm = fmaxf(tm, fmaxf(fmaxf(a0, a1), fmaxf(a2, a3)));
        }
        tm = fmaxf(tm, __shfl_xor(tm, 16));
        tm = fmaxf(tm, __shfl_xor(tm, 32));

        // ---- T13 defer-max: only rescale when the max moved by > 8 (base-2) ----
        if (__any(tm > m_s + 8.f)) {
            float mnew = fmaxf(m_s, tm);
            float al = EXP2F(m_s - mnew);     // first active tile: exp2(-huge) = 0
            m_s = mnew;
            l_s *= al;
#pragma unroll
            for (int n = 0; n < 8; ++n) acc2[n] *= al;
        }

        // ---- P = mask ? 2^(S - m) : 0 ; pack to per-wave LDS (B-frag route) ----
        unsigned short* pwv = s_P + wave * (WROWS * SP_STRIDE) + l15 * SP_STRIDE + quad * 4;
        float ps = 0.f;
#pragma unroll
        for (int nt = 0; nt < 4; ++nt) {
            float p0 = bit[nt][0] ? EXP2F(sfr[nt][0] - m_s) : 0.f;
            float p1 = bit[nt][1] ? EXP2F(sfr[nt][1] - m_s) : 0.f;
            float p2 = bit[nt][2] ? EXP2F(sfr[nt][2] - m_s) : 0.f;
            float p3 = bit[nt][3] ? EXP2F(sfr[nt][3] - m_s) : 0.f;
            ps += (p0 + p1) + (p2 + p3);
            ushort4 h;
            h.x = f2bf(p0); h.y = f2bf(p1); h.z = f2bf(p2); h.w = f2bf(p3);
            *(ushort4*)(pwv + nt * 16) = h;   // s_P[b=l15][z' = 16nt + 4quad + 0..3]
        }
        ps += __shfl_xor(ps, 16);
        ps += __shfl_xor(ps, 32);
        l_s += ps;

        // ---- GEMM2 (O^T): acc2[nt2] += embT_rows @ P^T  (K = 64 via two slices) ----
        const unsigned short* pb = s_P + wave * (WROWS * SP_STRIDE) + l15 * SP_STRIDE + quad * 8;
        bf16x8 pA0 = *(const bf16x8*)(pb);        // P[b=l15][z = quad*8 + j], z<32
        bf16x8 pA1 = *(const bf16x8*)(pb + 32);   // z >= 32
#pragma unroll
        for (int nt2 = 0; nt2 < 8; ++nt2) {
            const unsigned short* tb = s_embT + (nt2 * 16 + l15) * SEMBT_STRIDE + quad * 8;
            bf16x8 e0 = *(const bf16x8*)(tb);
            bf16x8 e1 = *(const bf16x8*)(tb + 32);
            acc2[nt2] = __builtin_amdgcn_mfma_f32_16x16x32_bf16(e0, pA0, acc2[nt2], 0, 0, 0);
            acc2[nt2] = __builtin_amdgcn_mfma_f32_16x16x32_bf16(e1, pA1, acc2[nt2], 0, 0, 0);
        }

#pragma unroll
        for (int nt = 0; nt < 4; ++nt) mc[nt] = mn[nt];
    }

    // ---- epilogue: O rows are lane-local -> 8 vector stores; reduce cnt across quads ----
    {
        float* orow = ws + WS_O + ((size_t)ch * B_SZ + brow) * D_SZ;
#pragma unroll
        for (int nt2 = 0; nt2 < 8; ++nt2) {
            *(f32x4*)(orow + nt2 * 16 + quad * 4) = acc2[nt2];
        }
    }
    cnt += __shfl_xor(cnt, 16);
    cnt += __shfl_xor(cnt, 32);
    if (lane < 16) {
        ws[WS_M + ch * B_SZ + brow] = m_s;
        ws[WS_L + ch * B_SZ + brow] = l_s;
        ws[WS_C + ch * B_SZ + brow] = (float)cnt;
    }
}

__global__ __launch_bounds__(128) void attn_reduce(
    const float* __restrict__ ws, float* __restrict__ out)
{
    const int b = blockIdx.x;
    const int d = threadIdx.x;
    const float* mP = ws + WS_M;
    const float* lP = ws + WS_L;
    const float* cP = ws + WS_C;

    float M = -1e30f;
#pragma unroll
    for (int c = 0; c < NZ; ++c) M = fmaxf(M, mP[c * B_SZ + b]);

    float L = 0.f, C = 0.f, acc = 0.f;
#pragma unroll
    for (int c = 0; c < NZ; ++c) {
        float w = EXP2F(mP[c * B_SZ + b] - M);
        L += lP[c * B_SZ + b] * w;
        C += cP[c * B_SZ + b];
        acc += ws[WS_O + ((size_t)c * B_SZ + b) * D_SZ + d] * w;
    }
    float cntv = fmaxf(C, 1.0f);
    out[(size_t)b * D_SZ + d] = (L > 0.f) ? acc / (L * cntv) : 0.f;
}

extern "C" void kernel_launch(void* const* d_in, const int* in_sizes, int n_in,
                              void* d_out, int out_size, void* d_ws, size_t ws_size,
                              hipStream_t stream) {
    (void)in_sizes; (void)n_in; (void)out_size; (void)ws_size;
    const int*   zs  = (const int*)  d_in[0];
    const float* ctx = (const float*)d_in[1];
    const float* emb = (const float*)d_in[2];
    float* out = (float*)d_out;
    float* ws  = (float*)d_ws;

    unsigned short* embR = (unsigned short*)(ws + WS_TAB);
    unsigned short* embT = embR + (size_t)Z_SZ * D_SZ;

    prep<<<NB_TAB, 256, 0, stream>>>(emb, embR, embT);

    dim3 grid1(B_SZ / TBLK, NZ);   // (16, 32)
    attn_part<<<grid1, 256, 0, stream>>>(zs, ctx, embR, embT, ws);
    attn_reduce<<<B_SZ, 128, 0, stream>>>(ws, out);
}